// Round 14
// baseline (266.208 us; speedup 1.0000x reference)
//
#include <hip/hip_runtime.h>
#include <math.h>

#define N_ENT  50000
#define N_REL  500
#define N_EDGE 800000
#define D      100
#define ALPHA  0.2f

#define SCAN_B 256
#define NBLK_SCAN ((N_ENT + SCAN_B - 1) / SCAN_B)   // 196

// ---------------------------------------------------------------------------
// K1: Y = X @ W, k-split W-in-registers version.
//  waves 0-1 (t in [0,100)):    half0, c = t,      k in [0,52),  w[52] in VGPRs
//  waves 2-3 (t in [128,228)):  half1, c = t-128,  k in [52,100), w[48] in VGPRs
//  X tile (50 rows) in LDS; reads are float4 same-address broadcasts.
//  Halves combine via P[5][100] LDS exchange every 5 rows.
//  Idle threads (t in [100,128) u [228,256)) zero deg[] (56/block * 1010 blocks).
// ---------------------------------------------------------------------------
#define PROJ_TPB  256
#define PROJ_RPB  50
#define ENT_BLKS  (N_ENT / PROJ_RPB)          // 1000
#define REL_BLKS  (N_REL / PROJ_RPB)          // 10

__global__ __launch_bounds__(PROJ_TPB) void proj_kernel(const float* __restrict__ Xe,
                                                        const float* __restrict__ Xr,
                                                        const float* __restrict__ W,
                                                        float* __restrict__ Ye,
                                                        float* __restrict__ Yr,
                                                        int* __restrict__ deg) {
    __shared__ float Xs[PROJ_RPB * D];    // 20 KB
    __shared__ float P[5][D];             // 2 KB exchange
    int t = threadIdx.x;

    const float* X; float* Y; size_t xbase;
    if (blockIdx.x < ENT_BLKS) {
        X = Xe; Y = Ye; xbase = (size_t)blockIdx.x * PROJ_RPB * D;
    } else {
        X = Xr; Y = Yr; xbase = (size_t)(blockIdx.x - ENT_BLKS) * PROJ_RPB * D;
    }

    int half, c;
    if (t < 100)                { half = 0; c = t; }
    else if (t >= 128 && t < 228) { half = 1; c = t - 128; }
    else                        { half = -1; c = 0; }

    // idle threads zero deg[]: 56 per block
    if (half < 0) {
        int idx = (t < 128) ? (t - 100) : (28 + (t - 228));
        int j = blockIdx.x * 56 + idx;
        if (j < N_ENT) deg[j] = 0;
    }

    // stage X tile (coalesced)
    for (int i = t; i < PROJ_RPB * D; i += PROJ_TPB)
        Xs[i] = X[xbase + i];

    // W slice into registers (coalesced across lanes for each k; L1/L2-hot)
    float w[52];
    if (half == 0) {
        #pragma unroll
        for (int k = 0; k < 52; ++k) w[k] = W[k * D + c];
    } else if (half == 1) {
        #pragma unroll
        for (int k = 0; k < 48; ++k) w[k] = W[(52 + k) * D + c];
    }
    __syncthreads();

    for (int g = 0; g < 10; ++g) {
        int r0 = g * 5;
        float a[5] = {0.f, 0.f, 0.f, 0.f, 0.f};
        if (half == 0) {
            #pragma unroll
            for (int r = 0; r < 5; ++r) {
                const float4* xr = (const float4*)&Xs[(r0 + r) * D];
                #pragma unroll
                for (int q = 0; q < 13; ++q) {
                    float4 xv = xr[q];
                    a[r] = fmaf(xv.x, w[4*q    ], a[r]);
                    a[r] = fmaf(xv.y, w[4*q + 1], a[r]);
                    a[r] = fmaf(xv.z, w[4*q + 2], a[r]);
                    a[r] = fmaf(xv.w, w[4*q + 3], a[r]);
                }
            }
        } else if (half == 1) {
            #pragma unroll
            for (int r = 0; r < 5; ++r) {
                const float4* xr = (const float4*)&Xs[(r0 + r) * D] + 13;
                #pragma unroll
                for (int q = 0; q < 12; ++q) {
                    float4 xv = xr[q];
                    a[r] = fmaf(xv.x, w[4*q    ], a[r]);
                    a[r] = fmaf(xv.y, w[4*q + 1], a[r]);
                    a[r] = fmaf(xv.z, w[4*q + 2], a[r]);
                    a[r] = fmaf(xv.w, w[4*q + 3], a[r]);
                }
            }
            #pragma unroll
            for (int r = 0; r < 5; ++r) P[r][c] = a[r];
        }
        __syncthreads();
        if (half == 0) {
            #pragma unroll
            for (int r = 0; r < 5; ++r)
                Y[xbase + (size_t)(r0 + r) * D + c] = a[r] + P[r][c];
        }
        __syncthreads();
    }
}

// ---------------------------------------------------------------------------
// CSR build: degree count -> 3-kernel parallel scan -> fill buckets
// ---------------------------------------------------------------------------
__global__ void degree_kernel(const int* __restrict__ h_idx, int* __restrict__ deg) {
    int e = blockIdx.x * blockDim.x + threadIdx.x;
    if (e < N_EDGE) atomicAdd(&deg[h_idx[e]], 1);
}

__global__ void scan1_kernel(const int* __restrict__ deg, int* __restrict__ bsum) {
    __shared__ int s[SCAN_B];
    int i = blockIdx.x * SCAN_B + threadIdx.x;
    s[threadIdx.x] = (i < N_ENT) ? deg[i] : 0;
    __syncthreads();
    for (int off = SCAN_B / 2; off; off >>= 1) {
        if (threadIdx.x < off) s[threadIdx.x] += s[threadIdx.x + off];
        __syncthreads();
    }
    if (threadIdx.x == 0) bsum[blockIdx.x] = s[0];
}

__global__ void scan2_kernel(const int* __restrict__ bsum, int* __restrict__ boff) {
    __shared__ int s[SCAN_B];
    int tid = threadIdx.x;
    int v = (tid < NBLK_SCAN) ? bsum[tid] : 0;
    s[tid] = v;
    __syncthreads();
    for (int off = 1; off < SCAN_B; off <<= 1) {
        int x = (tid >= off) ? s[tid - off] : 0;
        __syncthreads();
        s[tid] += x;
        __syncthreads();
    }
    if (tid < NBLK_SCAN) boff[tid] = s[tid] - v;   // exclusive
}

__global__ void scan3_kernel(const int* __restrict__ deg, const int* __restrict__ boff,
                             int* __restrict__ rowptr, int* __restrict__ cursor) {
    __shared__ int s[SCAN_B];
    int tid = threadIdx.x;
    int i = blockIdx.x * SCAN_B + tid;
    int v = (i < N_ENT) ? deg[i] : 0;
    s[tid] = v;
    __syncthreads();
    for (int off = 1; off < SCAN_B; off <<= 1) {
        int x = (tid >= off) ? s[tid - off] : 0;
        __syncthreads();
        s[tid] += x;
        __syncthreads();
    }
    int excl = s[tid] - v + boff[blockIdx.x];
    if (i < N_ENT) { rowptr[i] = excl; cursor[i] = excl; }
    if (i == N_ENT - 1) rowptr[N_ENT] = excl + v;
}

__global__ void fill_kernel(const int* __restrict__ h_idx, const int* __restrict__ t_idx,
                            const int* __restrict__ etype, int* __restrict__ cursor,
                            int2* __restrict__ tr_sorted) {
    int e = blockIdx.x * blockDim.x + threadIdx.x;
    if (e >= N_EDGE) return;
    int h = h_idx[e];
    int pos = atomicAdd(&cursor[h], 1);
    tr_sorted[pos] = make_int2(t_idx[e], etype[e]);
}

// ---------------------------------------------------------------------------
// Fused kernel: one head per 32-lane half-wave, float4 per lane (25 active),
// online softmax with SINGLE exp per edge, unroll-by-2. (unchanged — BW-bound)
// ---------------------------------------------------------------------------
__device__ __forceinline__ float edge_reduce32(const float4& eh, const float4& v) {
    float dx = eh.x + v.x, dy = eh.y + v.y, dz = eh.z + v.z, dw = eh.w + v.w;
    float s = dx * dx;
    s = fmaf(dy, dy, s);
    s = fmaf(dz, dz, s);
    s = fmaf(dw, dw, s);
    #pragma unroll
    for (int off = 16; off; off >>= 1) s += __shfl_xor(s, off, 32);
    return sqrtf(s);                       // leaky_relu identity (s >= 0)
}

__device__ __forceinline__ void online_update(float sc, const float4& v,
                                              float& m, float& den, float4& acc) {
    float d  = sc - m;
    float e  = __expf(-fabsf(d));
    float scale = (d >= 0.f) ? e : 1.f;
    float ex    = (d >= 0.f) ? 1.f : e;
    m = fmaxf(m, sc);
    den   = den * scale + ex;
    acc.x = acc.x * scale - v.x * ex;
    acc.y = acc.y * scale - v.y * ex;
    acc.z = acc.z * scale - v.z * ex;
    acc.w = acc.w * scale - v.w * ex;
}

__global__ __launch_bounds__(256) void fused_kernel(const float* __restrict__ ent,
                                                    const float* __restrict__ rel,
                                                    const int* __restrict__ rowptr,
                                                    const int2* __restrict__ tr_sorted,
                                                    float* __restrict__ out) {
    int head = blockIdx.x * 8 + (threadIdx.x >> 5);   // 8 half-waves per block
    int lane = threadIdx.x & 31;
    if (head >= N_ENT) return;                        // grid exact: 6250*8
    int beg = rowptr[head], end = rowptr[head + 1];

    float4 eh = make_float4(0.f, 0.f, 0.f, 0.f);
    if (lane < 25) eh = ((const float4*)(ent + (size_t)head * D))[lane];

    float  m   = -INFINITY;
    float  den = 0.f;
    float4 acc = make_float4(0.f, 0.f, 0.f, 0.f);

    int i = beg;
    for (; i + 1 < end; i += 2) {
        int2 e0 = tr_sorted[i];
        int2 e1 = tr_sorted[i + 1];
        float4 v0 = make_float4(0.f, 0.f, 0.f, 0.f);
        float4 v1 = make_float4(0.f, 0.f, 0.f, 0.f);
        if (lane < 25) {
            float4 et0 = ((const float4*)(ent + (size_t)e0.x * D))[lane];
            float4 er0 = ((const float4*)(rel + (size_t)e0.y * D))[lane];
            float4 et1 = ((const float4*)(ent + (size_t)e1.x * D))[lane];
            float4 er1 = ((const float4*)(rel + (size_t)e1.y * D))[lane];
            v0 = make_float4(er0.x - et0.x, er0.y - et0.y, er0.z - et0.z, er0.w - et0.w);
            v1 = make_float4(er1.x - et1.x, er1.y - et1.y, er1.z - et1.z, er1.w - et1.w);
        }
        float sc0 = edge_reduce32(eh, v0);
        float sc1 = edge_reduce32(eh, v1);
        online_update(sc0, v0, m, den, acc);
        online_update(sc1, v1, m, den, acc);
    }
    if (i < end) {
        int2 e0 = tr_sorted[i];
        float4 v = make_float4(0.f, 0.f, 0.f, 0.f);
        if (lane < 25) {
            float4 et = ((const float4*)(ent + (size_t)e0.x * D))[lane];
            float4 er = ((const float4*)(rel + (size_t)e0.y * D))[lane];
            v = make_float4(er.x - et.x, er.y - et.y, er.z - et.z, er.w - et.w);
        }
        float sc = edge_reduce32(eh, v);
        online_update(sc, v, m, den, acc);
    }

    float inv = 1.f / (den + 1e-16f);
    float ox = acc.x * inv, oy = acc.y * inv, oz = acc.z * inv, ow = acc.w * inv;
    ox = ox > 0.f ? ox : expm1f(ox);           // ELU
    oy = oy > 0.f ? oy : expm1f(oy);
    oz = oz > 0.f ? oz : expm1f(oz);
    ow = ow > 0.f ? ow : expm1f(ow);
    if (lane < 25)
        ((float4*)(out + (size_t)head * D))[lane] = make_float4(ox, oy, oz, ow);
}

extern "C" void kernel_launch(void* const* d_in, const int* in_sizes, int n_in,
                              void* d_out, int out_size, void* d_ws, size_t ws_size,
                              hipStream_t stream) {
    const float* entity_emb = (const float*)d_in[0];   // [N_ENT, D]
    const float* rel_emb    = (const float*)d_in[1];   // [N_REL, D]
    const float* W          = (const float*)d_in[2];   // [D, D]
    const int*   edge_index = (const int*)d_in[3];     // [2, N_EDGE]
    const int*   edge_type  = (const int*)d_in[4];     // [N_EDGE]
    float*       out        = (float*)d_out;           // [N_ENT, D]

    const int* h_idx = edge_index;             // row 0: head/destination
    const int* t_idx = edge_index + N_EDGE;    // row 1: tail/source

    // workspace layout (~27 MB)
    float* ent       = (float*)d_ws;                    // 5,000,000 f
    float* rel       = ent + (size_t)N_ENT * D;         //    50,000 f
    int*   deg       = (int*)(rel + (size_t)N_REL * D); //    50,000 i
    int*   rowptr    = deg + N_ENT;                     //    50,001 i
    int*   cursor    = rowptr + (N_ENT + 1);            //    50,000 i
    int*   bsum      = cursor + N_ENT;                  //       256 i
    int*   boff      = bsum + SCAN_B;                   //       256 i
    int2*  tr_sorted = (int2*)(boff + SCAN_B);          //   800,000 int2

    // projections (ent + rel in one launch; idle threads zero deg[])
    proj_kernel<<<ENT_BLKS + REL_BLKS, PROJ_TPB, 0, stream>>>(entity_emb, rel_emb,
                                                              W, ent, rel, deg);

    // CSR build: degree -> 3-kernel parallel scan -> fill
    degree_kernel<<<(N_EDGE + 255) / 256, 256, 0, stream>>>(h_idx, deg);
    scan1_kernel<<<NBLK_SCAN, SCAN_B, 0, stream>>>(deg, bsum);
    scan2_kernel<<<1, SCAN_B, 0, stream>>>(bsum, boff);
    scan3_kernel<<<NBLK_SCAN, SCAN_B, 0, stream>>>(deg, boff, rowptr, cursor);
    fill_kernel<<<(N_EDGE + 255) / 256, 256, 0, stream>>>(h_idx, t_idx, edge_type,
                                                          cursor, tr_sorted);

    // fused: one head per 32-lane half-wave (8 heads / 256-thread block)
    fused_kernel<<<N_ENT / 8, 256, 0, stream>>>(ent, rel, rowptr, tr_sorted, out);
}

// Round 15
// 228.921 us; speedup vs baseline: 1.1629x; 1.1629x over previous
//
#include <hip/hip_runtime.h>
#include <math.h>

#define N_ENT  50000
#define N_REL  500
#define N_EDGE 800000
#define D      100
#define ALPHA  0.2f

#define SCAN_B 256
#define NBLK_SCAN ((N_ENT + SCAN_B - 1) / SCAN_B)   // 196

// ---------------------------------------------------------------------------
// K_A: block-range-split dispatch.
//   blocks [0, 1010):          Y = X@W (k-split W-in-registers, R14 body)
//   blocks [1010, 1010+782):   rank[e] = atomicAdd(cnt[h[e]], 1)  (int4 loads)
// The rank pass's atomic latency hides under proj's FMA work.
// ---------------------------------------------------------------------------
#define PROJ_TPB  256
#define PROJ_RPB  50
#define ENT_BLKS  (N_ENT / PROJ_RPB)          // 1000
#define REL_BLKS  (N_REL / PROJ_RPB)          // 10
#define PROJ_BLKS (ENT_BLKS + REL_BLKS)       // 1010
#define RANK_BLKS ((N_EDGE + 1023) / 1024)    // 782 (4 edges/thread)

__global__ __launch_bounds__(PROJ_TPB) void proj_rank_kernel(const float* __restrict__ Xe,
                                                             const float* __restrict__ Xr,
                                                             const float* __restrict__ W,
                                                             float* __restrict__ Ye,
                                                             float* __restrict__ Yr,
                                                             const int* __restrict__ h_idx,
                                                             int* __restrict__ cnt,
                                                             unsigned short* __restrict__ rank) {
    int t = threadIdx.x;

    if (blockIdx.x >= PROJ_BLKS) {
        // ---- rank-counting blocks ----
        int eb = (blockIdx.x - PROJ_BLKS) * 1024 + t * 4;
        if (eb + 3 < N_EDGE) {
            int4 h4 = *(const int4*)(h_idx + eb);
            rank[eb    ] = (unsigned short)atomicAdd(&cnt[h4.x], 1);
            rank[eb + 1] = (unsigned short)atomicAdd(&cnt[h4.y], 1);
            rank[eb + 2] = (unsigned short)atomicAdd(&cnt[h4.z], 1);
            rank[eb + 3] = (unsigned short)atomicAdd(&cnt[h4.w], 1);
        } else {
            for (int e = eb; e < N_EDGE; ++e)
                rank[e] = (unsigned short)atomicAdd(&cnt[h_idx[e]], 1);
        }
        return;
    }

    // ---- projection blocks (k-split, W slices in VGPRs) ----
    __shared__ float Xs[PROJ_RPB * D];    // 20 KB
    __shared__ float P[5][D];             // 2 KB exchange

    const float* X; float* Y; size_t xbase;
    if (blockIdx.x < ENT_BLKS) {
        X = Xe; Y = Ye; xbase = (size_t)blockIdx.x * PROJ_RPB * D;
    } else {
        X = Xr; Y = Yr; xbase = (size_t)(blockIdx.x - ENT_BLKS) * PROJ_RPB * D;
    }

    int half, c;
    if (t < 100)                  { half = 0; c = t; }
    else if (t >= 128 && t < 228) { half = 1; c = t - 128; }
    else                          { half = -1; c = 0; }

    for (int i = t; i < PROJ_RPB * D; i += PROJ_TPB)
        Xs[i] = X[xbase + i];

    float w[52];
    if (half == 0) {
        #pragma unroll
        for (int k = 0; k < 52; ++k) w[k] = W[k * D + c];
    } else if (half == 1) {
        #pragma unroll
        for (int k = 0; k < 48; ++k) w[k] = W[(52 + k) * D + c];
    }
    __syncthreads();

    for (int g = 0; g < 10; ++g) {
        int r0 = g * 5;
        float a[5] = {0.f, 0.f, 0.f, 0.f, 0.f};
        if (half == 0) {
            #pragma unroll
            for (int r = 0; r < 5; ++r) {
                const float4* xr = (const float4*)&Xs[(r0 + r) * D];
                #pragma unroll
                for (int q = 0; q < 13; ++q) {
                    float4 xv = xr[q];
                    a[r] = fmaf(xv.x, w[4*q    ], a[r]);
                    a[r] = fmaf(xv.y, w[4*q + 1], a[r]);
                    a[r] = fmaf(xv.z, w[4*q + 2], a[r]);
                    a[r] = fmaf(xv.w, w[4*q + 3], a[r]);
                }
            }
        } else if (half == 1) {
            #pragma unroll
            for (int r = 0; r < 5; ++r) {
                const float4* xr = (const float4*)&Xs[(r0 + r) * D] + 13;
                #pragma unroll
                for (int q = 0; q < 12; ++q) {
                    float4 xv = xr[q];
                    a[r] = fmaf(xv.x, w[4*q    ], a[r]);
                    a[r] = fmaf(xv.y, w[4*q + 1], a[r]);
                    a[r] = fmaf(xv.z, w[4*q + 2], a[r]);
                    a[r] = fmaf(xv.w, w[4*q + 3], a[r]);
                }
            }
            #pragma unroll
            for (int r = 0; r < 5; ++r) P[r][c] = a[r];
        }
        __syncthreads();
        if (half == 0) {
            #pragma unroll
            for (int r = 0; r < 5; ++r)
                Y[xbase + (size_t)(r0 + r) * D + c] = a[r] + P[r][c];
        }
        __syncthreads();
    }
}

// ---------------------------------------------------------------------------
// 3-kernel parallel scan over cnt -> rowptr
// ---------------------------------------------------------------------------
__global__ void scan1_kernel(const int* __restrict__ cnt, int* __restrict__ bsum) {
    __shared__ int s[SCAN_B];
    int i = blockIdx.x * SCAN_B + threadIdx.x;
    s[threadIdx.x] = (i < N_ENT) ? cnt[i] : 0;
    __syncthreads();
    for (int off = SCAN_B / 2; off; off >>= 1) {
        if (threadIdx.x < off) s[threadIdx.x] += s[threadIdx.x + off];
        __syncthreads();
    }
    if (threadIdx.x == 0) bsum[blockIdx.x] = s[0];
}

__global__ void scan2_kernel(const int* __restrict__ bsum, int* __restrict__ boff) {
    __shared__ int s[SCAN_B];
    int tid = threadIdx.x;
    int v = (tid < NBLK_SCAN) ? bsum[tid] : 0;
    s[tid] = v;
    __syncthreads();
    for (int off = 1; off < SCAN_B; off <<= 1) {
        int x = (tid >= off) ? s[tid - off] : 0;
        __syncthreads();
        s[tid] += x;
        __syncthreads();
    }
    if (tid < NBLK_SCAN) boff[tid] = s[tid] - v;   // exclusive
}

__global__ void scan3_kernel(const int* __restrict__ cnt, const int* __restrict__ boff,
                             int* __restrict__ rowptr) {
    __shared__ int s[SCAN_B];
    int tid = threadIdx.x;
    int i = blockIdx.x * SCAN_B + tid;
    int v = (i < N_ENT) ? cnt[i] : 0;
    s[tid] = v;
    __syncthreads();
    for (int off = 1; off < SCAN_B; off <<= 1) {
        int x = (tid >= off) ? s[tid - off] : 0;
        __syncthreads();
        s[tid] += x;
        __syncthreads();
    }
    int excl = s[tid] - v + boff[blockIdx.x];
    if (i < N_ENT) rowptr[i] = excl;
    if (i == N_ENT - 1) rowptr[N_ENT] = excl + v;
}

// ---------------------------------------------------------------------------
// scatter: tr_sorted[rowptr[h] + rank[e]] = {t, r}   (NO atomics)
// ---------------------------------------------------------------------------
__global__ void scatter_kernel(const int* __restrict__ h_idx, const int* __restrict__ t_idx,
                               const int* __restrict__ etype,
                               const int* __restrict__ rowptr,
                               const unsigned short* __restrict__ rank,
                               int2* __restrict__ tr_sorted) {
    int e = blockIdx.x * blockDim.x + threadIdx.x;
    if (e >= N_EDGE) return;
    int h = h_idx[e];
    int pos = rowptr[h] + (int)rank[e];
    tr_sorted[pos] = make_int2(t_idx[e], etype[e]);
}

// ---------------------------------------------------------------------------
// Fused kernel: one head per 32-lane half-wave, float4 per lane (25 active),
// online softmax with SINGLE exp per edge, unroll-by-2. (unchanged)
// ---------------------------------------------------------------------------
__device__ __forceinline__ float edge_reduce32(const float4& eh, const float4& v) {
    float dx = eh.x + v.x, dy = eh.y + v.y, dz = eh.z + v.z, dw = eh.w + v.w;
    float s = dx * dx;
    s = fmaf(dy, dy, s);
    s = fmaf(dz, dz, s);
    s = fmaf(dw, dw, s);
    #pragma unroll
    for (int off = 16; off; off >>= 1) s += __shfl_xor(s, off, 32);
    return sqrtf(s);                       // leaky_relu identity (s >= 0)
}

__device__ __forceinline__ void online_update(float sc, const float4& v,
                                              float& m, float& den, float4& acc) {
    float d  = sc - m;
    float e  = __expf(-fabsf(d));
    float scale = (d >= 0.f) ? e : 1.f;
    float ex    = (d >= 0.f) ? 1.f : e;
    m = fmaxf(m, sc);
    den   = den * scale + ex;
    acc.x = acc.x * scale - v.x * ex;
    acc.y = acc.y * scale - v.y * ex;
    acc.z = acc.z * scale - v.z * ex;
    acc.w = acc.w * scale - v.w * ex;
}

__global__ __launch_bounds__(256) void fused_kernel(const float* __restrict__ ent,
                                                    const float* __restrict__ rel,
                                                    const int* __restrict__ rowptr,
                                                    const int2* __restrict__ tr_sorted,
                                                    float* __restrict__ out) {
    int head = blockIdx.x * 8 + (threadIdx.x >> 5);   // 8 half-waves per block
    int lane = threadIdx.x & 31;
    if (head >= N_ENT) return;                        // grid exact: 6250*8
    int beg = rowptr[head], end = rowptr[head + 1];

    float4 eh = make_float4(0.f, 0.f, 0.f, 0.f);
    if (lane < 25) eh = ((const float4*)(ent + (size_t)head * D))[lane];

    float  m   = -INFINITY;
    float  den = 0.f;
    float4 acc = make_float4(0.f, 0.f, 0.f, 0.f);

    int i = beg;
    for (; i + 1 < end; i += 2) {
        int2 e0 = tr_sorted[i];
        int2 e1 = tr_sorted[i + 1];
        float4 v0 = make_float4(0.f, 0.f, 0.f, 0.f);
        float4 v1 = make_float4(0.f, 0.f, 0.f, 0.f);
        if (lane < 25) {
            float4 et0 = ((const float4*)(ent + (size_t)e0.x * D))[lane];
            float4 er0 = ((const float4*)(rel + (size_t)e0.y * D))[lane];
            float4 et1 = ((const float4*)(ent + (size_t)e1.x * D))[lane];
            float4 er1 = ((const float4*)(rel + (size_t)e1.y * D))[lane];
            v0 = make_float4(er0.x - et0.x, er0.y - et0.y, er0.z - et0.z, er0.w - et0.w);
            v1 = make_float4(er1.x - et1.x, er1.y - et1.y, er1.z - et1.z, er1.w - et1.w);
        }
        float sc0 = edge_reduce32(eh, v0);
        float sc1 = edge_reduce32(eh, v1);
        online_update(sc0, v0, m, den, acc);
        online_update(sc1, v1, m, den, acc);
    }
    if (i < end) {
        int2 e0 = tr_sorted[i];
        float4 v = make_float4(0.f, 0.f, 0.f, 0.f);
        if (lane < 25) {
            float4 et = ((const float4*)(ent + (size_t)e0.x * D))[lane];
            float4 er = ((const float4*)(rel + (size_t)e0.y * D))[lane];
            v = make_float4(er.x - et.x, er.y - et.y, er.z - et.z, er.w - et.w);
        }
        float sc = edge_reduce32(eh, v);
        online_update(sc, v, m, den, acc);
    }

    float inv = 1.f / (den + 1e-16f);
    float ox = acc.x * inv, oy = acc.y * inv, oz = acc.z * inv, ow = acc.w * inv;
    ox = ox > 0.f ? ox : expm1f(ox);           // ELU
    oy = oy > 0.f ? oy : expm1f(oy);
    oz = oz > 0.f ? oz : expm1f(oz);
    ow = ow > 0.f ? ow : expm1f(ow);
    if (lane < 25)
        ((float4*)(out + (size_t)head * D))[lane] = make_float4(ox, oy, oz, ow);
}

extern "C" void kernel_launch(void* const* d_in, const int* in_sizes, int n_in,
                              void* d_out, int out_size, void* d_ws, size_t ws_size,
                              hipStream_t stream) {
    const float* entity_emb = (const float*)d_in[0];   // [N_ENT, D]
    const float* rel_emb    = (const float*)d_in[1];   // [N_REL, D]
    const float* W          = (const float*)d_in[2];   // [D, D]
    const int*   edge_index = (const int*)d_in[3];     // [2, N_EDGE]
    const int*   edge_type  = (const int*)d_in[4];     // [N_EDGE]
    float*       out        = (float*)d_out;           // [N_ENT, D]

    const int* h_idx = edge_index;             // row 0: head/destination
    const int* t_idx = edge_index + N_EDGE;    // row 1: tail/source

    // workspace layout (~28.6 MB)
    float*          ent       = (float*)d_ws;                     // 5,000,000 f
    float*          rel       = ent + (size_t)N_ENT * D;          //    50,000 f
    int*            cnt       = (int*)(rel + (size_t)N_REL * D);  //    50,000 i
    int*            rowptr    = cnt + N_ENT;                      //    50,001 i
    int*            bsum      = rowptr + (N_ENT + 1);             //       256 i
    int*            boff      = bsum + SCAN_B;                    //       256 i
    unsigned short* rank      = (unsigned short*)(boff + SCAN_B); //   800,000 u16
    int2*           tr_sorted = (int2*)(rank + N_EDGE);           //   800,000 int2

    hipMemsetAsync(cnt, 0, N_ENT * sizeof(int), stream);

    // proj (blocks 0..1009) || rank-count (blocks 1010..1791)
    proj_rank_kernel<<<PROJ_BLKS + RANK_BLKS, PROJ_TPB, 0, stream>>>(
        entity_emb, rel_emb, W, ent, rel, h_idx, cnt, rank);

    // scan cnt -> rowptr
    scan1_kernel<<<NBLK_SCAN, SCAN_B, 0, stream>>>(cnt, bsum);
    scan2_kernel<<<1, SCAN_B, 0, stream>>>(bsum, boff);
    scan3_kernel<<<NBLK_SCAN, SCAN_B, 0, stream>>>(cnt, boff, rowptr);

    // atomic-free scatter
    scatter_kernel<<<(N_EDGE + 255) / 256, 256, 0, stream>>>(h_idx, t_idx, edge_type,
                                                             rowptr, rank, tr_sorted);

    // fused: one head per 32-lane half-wave (8 heads / 256-thread block)
    fused_kernel<<<N_ENT / 8, 256, 0, stream>>>(ent, rel, rowptr, tr_sorted, out);
}